// Round 3
// baseline (752.661 us; speedup 1.0000x reference)
//
#include <hip/hip_runtime.h>
#include <stdint.h>

#define NN 100000
#define EE 1600000
#define DD 256

typedef __bf16 bf16;
typedef __attribute__((ext_vector_type(8))) __bf16 bf16x8;
typedef __attribute__((ext_vector_type(4))) float f32x4;
typedef __attribute__((ext_vector_type(4))) unsigned int u32x4;
typedef __attribute__((ext_vector_type(8))) unsigned short u16x8;

typedef __attribute__((address_space(1))) const unsigned int g_u32c;
typedef __attribute__((address_space(3))) unsigned int lds_u32;

__device__ __forceinline__ float bflo(unsigned int u) {
    union { unsigned int u; float f; } x; x.u = u << 16; return x.f;
}
__device__ __forceinline__ float bfhi(unsigned int u) {
    union { unsigned int u; float f; } x; x.u = u & 0xFFFF0000u; return x.f;
}
__device__ __forceinline__ unsigned short f2bf(float f) {
    return __builtin_bit_cast(unsigned short, (__bf16)f);
}
__device__ __forceinline__ float mask_fac(const void* mask, size_t idx, int byteMode) {
    if (byteMode) return ((const unsigned char*)mask)[idx] ? 2.0f : 0.0f;
    return ((const unsigned int*)mask)[idx] ? 2.0f : 0.0f;
}

// ---------------------------------------------------------------------------
// CSR build (5 dispatches incl. memset)
// ---------------------------------------------------------------------------
__global__ void count_deg_k(const int* __restrict__ dst, int* __restrict__ cnt) {
    int e = blockIdx.x * 256 + threadIdx.x;
    if (e < EE) atomicAdd(&cnt[__builtin_nontemporal_load(dst + e)], 1);
}
// block-inclusive scan of (cnt+1), also emits dinv
__global__ __launch_bounds__(256) void scan_blk_k(const int* __restrict__ cnt,
                                                  int* __restrict__ part,
                                                  int* __restrict__ bsum,
                                                  float* __restrict__ dinv) {
    __shared__ int buf[256];
    int i = blockIdx.x * 256 + threadIdx.x;
    int v = 0;
    if (i < NN) { v = cnt[i] + 1; dinv[i] = rsqrtf((float)v); }   // +1 self-loop
    buf[threadIdx.x] = v;
    __syncthreads();
    for (int off = 1; off < 256; off <<= 1) {
        int t = (threadIdx.x >= off) ? buf[threadIdx.x - off] : 0;
        __syncthreads();
        buf[threadIdx.x] += t;
        __syncthreads();
    }
    if (i < NN) part[i] = buf[threadIdx.x];
    if (threadIdx.x == 255) bsum[blockIdx.x] = buf[255];
}
__global__ __launch_bounds__(512) void scan_top_k(const int* __restrict__ bsum,
                                                  int* __restrict__ bpre, int nb) {
    __shared__ int buf[512];
    int v = (threadIdx.x < (unsigned)nb) ? bsum[threadIdx.x] : 0;
    buf[threadIdx.x] = v;
    __syncthreads();
    for (int off = 1; off < 512; off <<= 1) {
        int t = (threadIdx.x >= off) ? buf[threadIdx.x - off] : 0;
        __syncthreads();
        buf[threadIdx.x] += t;
        __syncthreads();
    }
    if (threadIdx.x < (unsigned)nb) bpre[threadIdx.x] = buf[threadIdx.x] - v;
}
// finalize offs, write self-loop entry first in each segment, set cursor
__global__ void scan_fin_k(const int* __restrict__ part, const int* __restrict__ bpre,
                           const int* __restrict__ cnt, const float* __restrict__ dinv,
                           int* __restrict__ offs, int* __restrict__ cur,
                           int* __restrict__ cs, float* __restrict__ cw) {
    int i = blockIdx.x * 256 + threadIdx.x;
    if (i >= NN) return;
    int o1 = part[i] + bpre[blockIdx.x];
    offs[i + 1] = o1;
    if (i == 0) offs[0] = 0;
    int o = o1 - (cnt[i] + 1);
    cs[o] = i;
    float di = dinv[i];
    cw[o] = di * di;
    cur[i] = o + 1;
}
__global__ void fill_csr_k(const int* __restrict__ src, const int* __restrict__ dst,
                           const float* __restrict__ dinv, int* __restrict__ cur,
                           int* __restrict__ cs, float* __restrict__ cw) {
    int e = blockIdx.x * 256 + threadIdx.x;
    if (e >= EE) return;
    int s = __builtin_nontemporal_load(src + e);
    int d = __builtin_nontemporal_load(dst + e);
    int pos = atomicAdd(&cur[d], 1);
    cs[pos] = s;
    cw[pos] = dinv[s] * dinv[d];
}

// ---------------------------------------------------------------------------
// prep: Wt[n][k] = (bf16)W[k][n] for 3 weights (blocks 0..191) + mask probe (192)
// ---------------------------------------------------------------------------
__global__ __launch_bounds__(256) void prep_k(
    const float* __restrict__ W0, const float* __restrict__ W1, const float* __restrict__ W2,
    bf16* __restrict__ T0, bf16* __restrict__ T1, bf16* __restrict__ T2,
    const unsigned int* __restrict__ m, int* __restrict__ flag) {
    int b = blockIdx.x;
    if (b == 192) {
        if (threadIdx.x < 64) {
            unsigned int v = m[threadIdx.x];
            int bad = (v > 1u && v != 0x3F800000u) ? 1 : 0;
            unsigned long long bl = __ballot(bad);
            if (threadIdx.x == 0) *flag = (bl != 0ull) ? 1 : 0;
        }
        return;
    }
    const float* W = b < 64 ? W0 : (b < 128 ? W1 : W2);
    bf16*       T  = b < 64 ? T0 : (b < 128 ? T1 : T2);
    int bb = b & 63;
    __shared__ float tile[32][33];
    int bx = bb & 7, by = bb >> 3;
    int tx = threadIdx.x & 31, ty = threadIdx.x >> 5;
    #pragma unroll
    for (int r = 0; r < 32; r += 8)
        tile[ty + r][tx] = W[(size_t)(by * 32 + ty + r) * DD + bx * 32 + tx];
    __syncthreads();
    #pragma unroll
    for (int r = 0; r < 32; r += 8)
        T[(size_t)(bx * 32 + ty + r) * DD + by * 32 + tx] = (bf16)tile[tx][ty + r];
}

// ---------------------------------------------------------------------------
// bf16 MFMA GEMM, 128x128 tile, BK=64, XOR-swizzled LDS (rule-21: linear
// gload_lds dest + inverse-swizzled global source + swizzled ds_read).
// F32A=1: A is fp32, reg-staged with inline cvt (GEMM0, fuses omega cvt).
// EPI 1: +bias, relu, dropout(mask) -> bf16
// EPI 2: +bias, * z -> fp32 nt store (final output)
// ---------------------------------------------------------------------------
template <int EPI, int F32A>
__global__ __launch_bounds__(256) void gemm_k(
    const void* __restrict__ Ap, const bf16* __restrict__ Wt,
    const float* __restrict__ bias, const void* __restrict__ mask,
    const int* __restrict__ flagp, const float* __restrict__ z,
    void* __restrict__ outp) {
    __shared__ __align__(16) bf16 As[128 * 64];
    __shared__ __align__(16) bf16 Bs[128 * 64];
    int tid = threadIdx.x;
    int m0 = blockIdx.x * 128, n0 = blockIdx.y * 128;
    int wid = tid >> 6, lane = tid & 63;
    int wm = wid >> 1, wn = wid & 1;
    int lr = lane & 15, lk = lane >> 4;
    int rx = lr & 7;                         // row&7 for swizzled reads

    f32x4 acc[4][4] = {};

    for (int k0 = 0; k0 < DD; k0 += 64) {
        if (F32A) {
            const float* A = (const float*)Ap;
            #pragma unroll
            for (int i = 0; i < 4; i++) {
                int c = i * 256 + tid;           // chunk of 8 floats
                int row = c >> 3, s8 = c & 7;
                int gr = m0 + row; if (gr > NN - 1) gr = NN - 1;
                const float* srcp = A + (size_t)gr * DD + k0 + s8 * 8;
                float4 v0 = *(const float4*)srcp;
                float4 v1 = *(const float4*)(srcp + 4);
                u16x8 o = { f2bf(v0.x), f2bf(v0.y), f2bf(v0.z), f2bf(v0.w),
                            f2bf(v1.x), f2bf(v1.y), f2bf(v1.z), f2bf(v1.w) };
                *(u16x8*)(As + row * 64 + ((s8 ^ (row & 7)) * 8)) = o;
            }
        } else {
            const bf16* A = (const bf16*)Ap;
            #pragma unroll
            for (int i = 0; i < 4; i++) {
                int f = i * 256 + tid;           // 16B chunk
                int row = f >> 3;
                int scol = ((f & 7) ^ (row & 7)) * 8;
                int gr = m0 + row; if (gr > NN - 1) gr = NN - 1;
                __builtin_amdgcn_global_load_lds(
                    (g_u32c*)(A + (size_t)gr * DD + k0 + scol),
                    (lds_u32*)(As + (size_t)f * 8), 16, 0, 0);
            }
        }
        #pragma unroll
        for (int i = 0; i < 4; i++) {
            int f = i * 256 + tid;
            int row = f >> 3;
            int scol = ((f & 7) ^ (row & 7)) * 8;
            __builtin_amdgcn_global_load_lds(
                (g_u32c*)(Wt + (size_t)(n0 + row) * DD + k0 + scol),
                (lds_u32*)(Bs + (size_t)f * 8), 16, 0, 0);
        }
        __syncthreads();
        #pragma unroll
        for (int kk = 0; kk < 2; kk++) {
            bf16x8 af[4], bfr[4];
            #pragma unroll
            for (int mi = 0; mi < 4; mi++) {
                int r = wm * 64 + mi * 16 + lr;
                af[mi] = *(const bf16x8*)(As + r * 64 + (((kk * 4 + lk) ^ rx) * 8));
            }
            #pragma unroll
            for (int ni = 0; ni < 4; ni++) {
                int r = wn * 64 + ni * 16 + lr;
                bfr[ni] = *(const bf16x8*)(Bs + r * 64 + (((kk * 4 + lk) ^ rx) * 8));
            }
            #pragma unroll
            for (int mi = 0; mi < 4; mi++)
                #pragma unroll
                for (int ni = 0; ni < 4; ni++)
                    acc[mi][ni] = __builtin_amdgcn_mfma_f32_16x16x32_bf16(
                        af[mi], bfr[ni], acc[mi][ni], 0, 0, 0);
        }
        __syncthreads();
    }

    int bm = (EPI == 1) ? *flagp : 0;
    #pragma unroll
    for (int mi = 0; mi < 4; mi++) {
        #pragma unroll
        for (int r = 0; r < 4; r++) {
            int gr = m0 + wm * 64 + mi * 16 + lk * 4 + r;   // C/D: row=(lane>>4)*4+reg
            if (gr >= NN) continue;
            #pragma unroll
            for (int ni = 0; ni < 4; ni++) {
                int gc = n0 + wn * 64 + ni * 16 + lr;       // col = lane&15
                size_t idx = (size_t)gr * DD + gc;
                float v = acc[mi][ni][r] + bias[gc];
                if (EPI == 1) {
                    v = fmaxf(v, 0.0f) * mask_fac(mask, idx, bm);
                    ((bf16*)outp)[idx] = (bf16)v;
                } else {
                    v *= __builtin_nontemporal_load(z + idx);
                    __builtin_nontemporal_store(v, (float*)outp + idx);
                }
            }
        }
    }
}

// ---------------------------------------------------------------------------
// Pure CSR gather: out[n,:] = sum_e w[e] * t[src[e],:]   (bf16 rows, fp32 acc)
// One wave per node; 32 lanes x 16B cover one row -> 2 rows in flight/wave.
// ---------------------------------------------------------------------------
__global__ __launch_bounds__(256) void agg_k(
    const bf16* __restrict__ t, const int* __restrict__ offs,
    const int* __restrict__ cs, const float* __restrict__ cw,
    bf16* __restrict__ out) {
    int node = blockIdx.x * 4 + (threadIdx.x >> 6);
    if (node >= NN) return;
    int lane = threadIdx.x & 63;
    int half = lane >> 5;
    int lc = lane & 31;                       // col group: cols lc*8 .. lc*8+7
    int beg = offs[node], end = offs[node + 1];

    float acc[8] = {};
    const unsigned short* tb = (const unsigned short*)t;
    for (int base = beg; base < end; base += 64) {
        int nume = min(64, end - base);
        int sl = 0; float wl = 0.f;
        if (lane < nume) {
            sl = __builtin_nontemporal_load(cs + base + lane);
            wl = __builtin_nontemporal_load(cw + base + lane);
        }
        int nit = (nume + 1) >> 1;
        for (int j = 0; j < nit; j++) {
            int idx = 2 * j + half;           // idx>=nume -> wl==0, sl==0 (safe)
            int s   = __shfl(sl, idx);
            float w = __shfl(wl, idx);
            u32x4 u = *(const u32x4*)(tb + (size_t)s * DD + lc * 8);
            acc[0] = fmaf(w, bflo(u.x), acc[0]);
            acc[1] = fmaf(w, bfhi(u.x), acc[1]);
            acc[2] = fmaf(w, bflo(u.y), acc[2]);
            acc[3] = fmaf(w, bfhi(u.y), acc[3]);
            acc[4] = fmaf(w, bflo(u.z), acc[4]);
            acc[5] = fmaf(w, bfhi(u.z), acc[5]);
            acc[6] = fmaf(w, bflo(u.w), acc[6]);
            acc[7] = fmaf(w, bfhi(u.w), acc[7]);
        }
    }
    #pragma unroll
    for (int i = 0; i < 8; i++) acc[i] += __shfl_xor(acc[i], 32);
    if (half == 0) {
        u16x8 o = { f2bf(acc[0]), f2bf(acc[1]), f2bf(acc[2]), f2bf(acc[3]),
                    f2bf(acc[4]), f2bf(acc[5]), f2bf(acc[6]), f2bf(acc[7]) };
        __builtin_nontemporal_store(o, (u16x8*)((unsigned short*)out + (size_t)node * DD + lc * 8));
    }
}

// ---------------------------------------------------------------------------
extern "C" void kernel_launch(void* const* d_in, const int* in_sizes, int n_in,
                              void* d_out, int out_size, void* d_ws, size_t ws_size,
                              hipStream_t stream) {
    const float* z     = (const float*)d_in[0];
    const float* omega = (const float*)d_in[1];
    const int*   eidx  = (const int*)d_in[2];
    const float* W_lin = (const float*)d_in[3];
    const float* b_lin = (const float*)d_in[4];
    const float* W_g1  = (const float*)d_in[5];
    const float* b_g1  = (const float*)d_in[6];
    const float* W_g2  = (const float*)d_in[7];
    const float* b_g2  = (const float*)d_in[8];
    const void*  mask1 = d_in[9];
    const void*  mask2 = d_in[10];

    const int* e_src = eidx;
    const int* e_dst = eidx + EE;

    char* p = (char*)d_ws;
    size_t off = 0;
    auto alloc = [&](size_t bytes) -> char* {
        char* r = p + off;
        off = (off + bytes + 255) & ~(size_t)255;
        return r;
    };
    const int NB256 = (NN + 255) / 256;          // 391
    int*   flag = (int*)  alloc(4);
    int*   cnt  = (int*)  alloc((size_t)NN * 4);
    int*   offs = (int*)  alloc(((size_t)NN + 1) * 4);
    int*   cur  = (int*)  alloc((size_t)NN * 4);
    int*   part = (int*)  alloc((size_t)NN * 4);
    int*   bsum = (int*)  alloc(512 * 4);
    int*   bpre = (int*)  alloc(512 * 4);
    float* dinv = (float*)alloc((size_t)NN * 4);
    int*   cs   = (int*)  alloc((size_t)(EE + NN) * 4);
    float* cw   = (float*)alloc((size_t)(EE + NN) * 4);
    bf16*  WtL  = (bf16*) alloc((size_t)DD * DD * 2);
    bf16*  Wt1  = (bf16*) alloc((size_t)DD * DD * 2);
    bf16*  Wt2  = (bf16*) alloc((size_t)DD * DD * 2);
    const size_t NBH = (size_t)NN * DD * 2;      // 51.2 MB bf16 slab
    bf16*  S1   = (bf16*) alloc(NBH);
    bf16*  S2   = (bf16*) alloc(NBH);

    // --- CSR build ---
    hipMemsetAsync(cnt, 0, (size_t)NN * 4, stream);
    count_deg_k<<<EE / 256, 256, 0, stream>>>(e_dst, cnt);
    scan_blk_k <<<NB256, 256, 0, stream>>>(cnt, part, bsum, dinv);
    scan_top_k <<<1, 512, 0, stream>>>(bsum, bpre, NB256);
    scan_fin_k <<<NB256, 256, 0, stream>>>(part, bpre, cnt, dinv, offs, cur, cs, cw);
    fill_csr_k <<<EE / 256, 256, 0, stream>>>(e_src, e_dst, dinv, cur, cs, cw);

    // --- weight transpose-cvt + mask probe ---
    prep_k<<<193, 256, 0, stream>>>(W_lin, W_g1, W_g2, WtL, Wt1, Wt2,
                                    (const unsigned int*)mask1, flag);

    // --- pipeline: GCNConv reordered as (A_hat . X) . W ---
    dim3 ggrid((NN + 127) / 128, 2);
    // h0 = dropout(relu(omega @ W_lin + b_lin))        (f32 A, fused cvt) -> S1
    gemm_k<1, 1><<<ggrid, 256, 0, stream>>>(omega, WtL, b_lin, mask1, flag, nullptr, S1);
    // g1 = A_hat . h0                                   S1 -> S2
    agg_k<<<NN / 4, 256, 0, stream>>>(S1, offs, cs, cw, S2);
    // h1 = dropout(relu(g1 @ W_g1 + b_g1))              S2 -> S1
    gemm_k<1, 0><<<ggrid, 256, 0, stream>>>(S2, Wt1, b_g1, mask2, flag, nullptr, S1);
    // g2 = A_hat . h1                                   S1 -> S2
    agg_k<<<NN / 4, 256, 0, stream>>>(S1, offs, cs, cw, S2);
    // out = z * (g2 @ W_g2 + b_g2)                      S2 -> d_out (fp32, nt)
    gemm_k<2, 0><<<ggrid, 256, 0, stream>>>(S2, Wt2, b_g2, nullptr, flag, z, d_out);
}